// Round 2
// baseline (675.935 us; speedup 1.0000x reference)
//
#include <hip/hip_runtime.h>

// LiDAR volume renderer: N=8192 rays, S=768 steps, 20 semantic + 2 attr channels.
// out[ray][0]=depth, [1:3]=image(attr, masked w>1e-4), [3:23]=semantic, [23]=weights_sum
//
// R2: BLK=320 (5 waves). Since 320 % 5 == 0, flat float4 index p = t + 320k has
// p%5 == t%5, so each thread owns a FIXED channel-group g=t%5 of the 20-channel
// semantic row -> per-instruction lane-contiguous (coalesced) float4 loads,
// fixing R1's 80B-lane-stride 5x transaction amplification.

#define NSTEPS 768
#define NSEM 20
#define NOUT 24
#define BLK 320

static constexpr float kNear = 0.01f;
static constexpr float kFar  = 0.81f;
static constexpr float kWThresh = 1e-4f;

__global__ __launch_bounds__(BLK) void lidar_render_kernel(
    const float* __restrict__ sigma,   // [N, S]
    const float* __restrict__ sem,     // [N, S, 20]
    const float* __restrict__ attr,    // [N, S, 2]
    float* __restrict__ out)           // [N, 24]
{
    const int ray  = blockIdx.x;
    const int t    = threadIdx.x;
    const int lane = t & 63;
    const int wave = t >> 6;

    __shared__ float w_lds[NSTEPS];        // sigma staging, then weights
    __shared__ float wave_tot[4];
    __shared__ float acc_lds[BLK * 4];     // per-thread semantic partials
    __shared__ float red_d[5], red_w[5], red_i0[5], red_i1[5];

    // ---------- Phase 0: coalesced sigma -> LDS ----------
    const float* sp = sigma + (size_t)ray * NSTEPS;
    #pragma unroll
    for (int j = 0; j < 3; ++j) {
        int idx = t + BLK * j;
        if (idx < NSTEPS) w_lds[idx] = sp[idx];
    }
    __syncthreads();

    // ---------- Phase 1: weights via exp(-prefix sum), threads 0..255 ----------
    const float h  = (kFar - kNear) / (float)(NSTEPS - 1); // delta, s < S-1
    const float h2 = (kFar - kNear) / (float)NSTEPS;       // last delta

    float x0 = 0.f, x1 = 0.f, x2 = 0.f, local = 0.f, inc = 0.f;
    if (t < 256) {
        float sg0 = w_lds[3 * t], sg1 = w_lds[3 * t + 1], sg2 = w_lds[3 * t + 2];
        x0 = h * sg0;
        x1 = h * sg1;
        x2 = ((3 * t + 2) == (NSTEPS - 1) ? h2 : h) * sg2;
        local = x0 + x1 + x2;
        inc = local;
        #pragma unroll
        for (int d = 1; d < 64; d <<= 1) {
            float v = __shfl_up(inc, d, 64);
            if (lane >= d) inc += v;
        }
        if (lane == 63) wave_tot[wave] = inc;
    }
    __syncthreads();   // also: all sigma reads from w_lds complete before rewrites

    float depth_p = 0.f, wsum_p = 0.f;
    if (t < 256) {
        float base = inc - local;                  // exclusive within wave
        #pragma unroll
        for (int wv = 0; wv < 4; ++wv)
            if (wv < wave) base += wave_tot[wv];
        float T  = __expf(-base);
        float e0 = __expf(-x0), e1 = __expf(-x1), e2 = __expf(-x2);
        float w0 = T * (1.0f - e0);  T *= e0;
        float w1 = T * (1.0f - e1);  T *= e1;
        float w2 = T * (1.0f - e2);
        w_lds[3 * t]     = w0;
        w_lds[3 * t + 1] = w1;
        w_lds[3 * t + 2] = w2;
        const float z0 = kNear + h * (float)(3 * t);
        depth_p = w0 * z0 + w1 * (z0 + h) + w2 * (z0 + 2.0f * h);
        wsum_p  = w0 + w1 + w2;
    }
    __syncthreads();

    // ---------- Phase 2a: semantic, fully coalesced float4 ----------
    const int sbase = t / 5;                 // starting step for this thread
    const float4* p4 = (const float4*)(sem + (size_t)ray * NSTEPS * NSEM) + t;
    float a0 = 0.f, a1 = 0.f, a2 = 0.f, a3 = 0.f;
    #pragma unroll
    for (int k = 0; k < 12; ++k) {
        float4 v = p4[(size_t)BLK * k];
        float w = w_lds[sbase + 64 * k];     // 5-lane broadcast, conflict-free
        a0 += w * v.x; a1 += w * v.y; a2 += w * v.z; a3 += w * v.w;
    }
    acc_lds[t * 4 + 0] = a0;
    acc_lds[t * 4 + 1] = a1;
    acc_lds[t * 4 + 2] = a2;
    acc_lds[t * 4 + 3] = a3;

    // ---------- Phase 2b: attr (masked), coalesced float4 = 2 steps ----------
    const float4* a4 = (const float4*)(attr + (size_t)ray * NSTEPS * 2);
    float ai0 = 0.f, ai1 = 0.f;
    #pragma unroll
    for (int k = 0; k < 2; ++k) {
        int p = t + BLK * k;
        if (p < (NSTEPS * 2) / 4) {
            float4 v = a4[p];
            float wA = w_lds[2 * p], wB = w_lds[2 * p + 1];
            if (wA > kWThresh) { ai0 += wA * v.x; ai1 += wA * v.y; }
            if (wB > kWThresh) { ai0 += wB * v.z; ai1 += wB * v.w; }
        }
    }

    // ---------- Phase 3: reductions ----------
    float dv = depth_p, wvs = wsum_p, i0 = ai0, i1 = ai1;
    #pragma unroll
    for (int d = 32; d >= 1; d >>= 1) {
        dv  += __shfl_xor(dv,  d, 64);
        wvs += __shfl_xor(wvs, d, 64);
        i0  += __shfl_xor(i0,  d, 64);
        i1  += __shfl_xor(i1,  d, 64);
    }
    if (lane == 0) {
        red_d[wave]  = dv;
        red_w[wave]  = wvs;
        red_i0[wave] = i0;
        red_i1[wave] = i1;
    }
    __syncthreads();

    if (t < NOUT) {
        float r;
        if (t == 0) {
            r = red_d[0] + red_d[1] + red_d[2] + red_d[3] + red_d[4];
        } else if (t == 1) {
            r = red_i0[0] + red_i0[1] + red_i0[2] + red_i0[3] + red_i0[4];
        } else if (t == 2) {
            r = red_i1[0] + red_i1[1] + red_i1[2] + red_i1[3] + red_i1[4];
        } else if (t == 23) {
            r = red_w[0] + red_w[1] + red_w[2] + red_w[3] + red_w[4];
        } else {
            const int c = t - 3;                  // channel 0..19
            r = 0.f;
            #pragma unroll 8
            for (int m = 0; m < 64; ++m)
                r += acc_lds[20 * m + c];         // lane-consecutive, conflict-free
        }
        out[(size_t)ray * NOUT + t] = r;
    }
}

extern "C" void kernel_launch(void* const* d_in, const int* in_sizes, int n_in,
                              void* d_out, int out_size, void* d_ws, size_t ws_size,
                              hipStream_t stream) {
    const float* sigma = (const float*)d_in[0];   // [8192, 768]
    const float* sem   = (const float*)d_in[1];   // [8192, 768, 20]
    const float* attr  = (const float*)d_in[2];   // [8192, 768, 2]
    float* out = (float*)d_out;                   // [8192, 24]

    const int n_rays = in_sizes[0] / NSTEPS;
    lidar_render_kernel<<<n_rays, BLK, 0, stream>>>(sigma, sem, attr, out);
}